// Round 6
// baseline (98.018 us; speedup 1.0000x reference)
//
#include <hip/hip_runtime.h>

// Problem constants
#define N_ 32
#define T_ 300
#define V_ 25
#define C_ 64      // C_IN
#define F_ 128
#define K_ 3
#define TB 2                       // timesteps per chunk
#define CH 3                       // chunks per block
#define TBLK (TB * CH)             // 6 timesteps per block
#define NGRP (T_ / TBLK)           // 50
#define NBLK (N_ * NGRP)           // 1600 blocks

typedef _Float16 f16;
typedef f16  f16x4v __attribute__((ext_vector_type(4)));
typedef f16  f16x8v __attribute__((ext_vector_type(8)));
typedef float f32x4v __attribute__((ext_vector_type(4)));

// workspace byte offsets
#define WS_WT 0         // f16 Wt[384][64]   = 49152 B
#define WS_A2 49152     // f16 A2[3][32][32] =  6144 B

// ---------------- prep: transpose/convert W, pad/convert A ----------------
__global__ void gcn_prep(const float* __restrict__ A, const float* __restrict__ W,
                         f16* __restrict__ Wt, f16* __restrict__ A2) {
    int tid = blockIdx.x * blockDim.x + threadIdx.x;
    if (tid < K_ * F_ * C_) {
        int d = tid >> 6, c = tid & 63;
        Wt[tid] = (f16)W[c * (K_ * F_) + d];
    }
    int t2 = tid - K_ * F_ * C_;
    if (t2 >= 0 && t2 < K_ * 32 * 32) {
        int k = t2 >> 10, r = t2 & 1023, w = r >> 5, v = r & 31;
        float val = (w < V_ && v < V_) ? A[(k * V_ + v) * V_ + w] : 0.0f;
        A2[t2] = (f16)val;
    }
}

// ---------------- fused streaming pipeline ----------------
// per chunk c (2 timesteps), per k: hT[d'][tv] = b[kF+d'] + sum_c x[tv][c]*Wt[kF+d'][c]
//                                   y[t][w][f] += sum_v A2[k][w][v] * hT[f][t*32+v]
// phases q=0..8: gemm2(q-1) || gemm1(q); hT parity q&1; one barrier per phase.
__global__ __launch_bounds__(256, 4) void gcn_fused(
    const float* __restrict__ x, const f16* __restrict__ Wt,
    const f16* __restrict__ A2g, const float* __restrict__ b,
    float* __restrict__ y)
{
    // x chunk: rows tv = t*32+v (v 25..31 zero), 64 cols, XOR-swizzled:
    //   byte = (tv*128 + c*2) ^ ((tv&7)<<4)
    __shared__ __align__(16) f16 x_lds[64 * 64];         // 8192 B
    // hT slices, swizzled: byte = (d*128 + tv*2) ^ ((d&7)<<4)
    __shared__ __align__(16) f16 hT_lds[2][128 * 64];    // 2 x 16384 B
    // total 40960 B -> 4 blocks/CU

    const int tid  = threadIdx.x;
    const int lane = tid & 63;
    const int wave = tid >> 6;
    const int l15  = lane & 15;
    const int lgr  = lane >> 4;       // 0..3
    const int koff = lgr * 8;

    const int n  = blockIdx.x / NGRP;
    const int t0 = (blockIdx.x % NGRP) * TBLK;

    const float* xbase = x + ((size_t)n * T_ + t0) * (V_ * C_);

    // ---- staging (T14): global -> regs (issued early) -> LDS (written late) ----
    float4 xstg[4];
    auto stage_load = [&](int c) {
        const float4* xs = (const float4*)(xbase + (size_t)c * TB * V_ * C_);
        #pragma unroll
        for (int i = 0; i < 4; ++i) {
            int idx = tid + i * 256;
            if (idx < TB * V_ * C_ / 4) xstg[i] = xs[idx];
        }
    };
    auto stage_write = [&]() {
        char* xb = (char*)x_lds;
        #pragma unroll
        for (int i = 0; i < 4; ++i) {
            int idx = tid + i * 256;
            if (idx < TB * V_ * C_ / 4) {
                int e = idx * 4;
                int t = e / (V_ * C_);
                int r = e - t * (V_ * C_);
                int v = r >> 6, c = r & 63;
                int row = t * 32 + v;
                f16x4v hv;
                hv[0] = (f16)xstg[i].x; hv[1] = (f16)xstg[i].y;
                hv[2] = (f16)xstg[i].z; hv[3] = (f16)xstg[i].w;
                int off = (row * 128 + c * 2) ^ ((row & 7) << 4);
                *(f16x4v*)(xb + off) = hv;
            }
        }
    };

    // zero rows v in [25,32) once (staging never touches them)
    if (tid < 224) {
        int e = tid * 4;
        int t = e / (7 * C_);
        int r = e - t * (7 * C_);
        int v = 25 + (r >> 6), c = r & 63;
        int row = t * 32 + v;
        int off = (row * 128 + c * 2) ^ ((row & 7) << 4);
        f16x4v z = {(f16)0.f, (f16)0.f, (f16)0.f, (f16)0.f};
        *(f16x4v*)((char*)x_lds + off) = z;
    }

    // per-lane bias: d = k*128 + wave*32 + nt*16 + l15
    float bias[K_][2];
    #pragma unroll
    for (int k = 0; k < K_; ++k)
        #pragma unroll
        for (int nt = 0; nt < 2; ++nt)
            bias[k][nt] = b[k * F_ + wave * 32 + nt * 16 + l15];

    f32x4v zero4 = {0.f, 0.f, 0.f, 0.f};
    f32x4v acc2[2][4];
    #pragma unroll
    for (int mt = 0; mt < 2; ++mt)
        #pragma unroll
        for (int nt = 0; nt < 4; ++nt)
            acc2[mt][nt] = zero4;

    const int t  = wave >> 1;          // step-2 timestep within chunk
    const int nh = (wave & 1) * 4;     // step-2 f-half
    const f16* wrow = Wt + (size_t)(wave * 32 + l15) * C_ + koff;

    // ---- GEMM1: D[tv][d'] -> hT buf (+bias) ----
    auto gemm1 = [&](int k, f16* buf) {
        f16x8v wfr[2][2];
        #pragma unroll
        for (int nt = 0; nt < 2; ++nt)
            #pragma unroll
            for (int kt = 0; kt < 2; ++kt)
                wfr[nt][kt] = *(const f16x8v*)(wrow + (size_t)(k * F_ + nt * 16) * C_ + kt * 32);
        f16x8v xa[4][2];
        #pragma unroll
        for (int mt = 0; mt < 4; ++mt) {
            int row = mt * 16 + l15;
            #pragma unroll
            for (int kt = 0; kt < 2; ++kt) {
                int off = (row * 128 + (kt * 32 + koff) * 2) ^ ((row & 7) << 4);
                xa[mt][kt] = *(const f16x8v*)((const char*)x_lds + off);
            }
        }
        f32x4v acc1[4][2];
        #pragma unroll
        for (int mt = 0; mt < 4; ++mt)
            #pragma unroll
            for (int nt = 0; nt < 2; ++nt)
                acc1[mt][nt] = zero4;
        #pragma unroll
        for (int kt = 0; kt < 2; ++kt)
            #pragma unroll
            for (int mt = 0; mt < 4; ++mt)
                #pragma unroll
                for (int nt = 0; nt < 2; ++nt)
                    acc1[mt][nt] = __builtin_amdgcn_mfma_f32_16x16x32_f16(
                        xa[mt][kt], wfr[nt][kt], acc1[mt][nt], 0, 0, 0);
        char* hb = (char*)buf;
        #pragma unroll
        for (int mt = 0; mt < 4; ++mt)
            #pragma unroll
            for (int nt = 0; nt < 2; ++nt) {
                int d = wave * 32 + nt * 16 + l15;
                float bv = bias[k][nt];
                f16x4v h4;
                #pragma unroll
                for (int r = 0; r < 4; ++r) h4[r] = (f16)(acc1[mt][nt][r] + bv);
                int off = (d * 128 + (mt * 16 + lgr * 4) * 2) ^ ((d & 7) << 4);
                *(f16x4v*)(hb + off) = h4;
            }
    };

    // ---- GEMM2: acc2 += A2_k @ hT ----
    auto gemm2 = [&](int k, const f16* buf) {
        f16x8v a2f[2];
        #pragma unroll
        for (int mt = 0; mt < 2; ++mt)
            a2f[mt] = *(const f16x8v*)(A2g + ((size_t)(k * 32 + mt * 16 + l15) * 32 + koff));
        const char* hb = (const char*)buf;
        #pragma unroll
        for (int nt = 0; nt < 4; ++nt) {
            int f = (nh + nt) * 16 + l15;
            int off = (f * 128 + (t * 32 + koff) * 2) ^ ((f & 7) << 4);
            f16x8v bv = *(const f16x8v*)(hb + off);
            #pragma unroll
            for (int mt = 0; mt < 2; ++mt)
                acc2[mt][nt] = __builtin_amdgcn_mfma_f32_16x16x32_f16(
                    a2f[mt], bv, acc2[mt][nt], 0, 0, 0);
        }
    };

    // ---- store y for chunk cc, then reset acc2 ----
    auto store_y = [&](int cc) {
        float* yr = y + (((size_t)n * T_ + (t0 + cc * TB + t)) * V_) * F_;
        #pragma unroll
        for (int mt = 0; mt < 2; ++mt) {
            int wb = mt * 16 + lgr * 4;
            #pragma unroll
            for (int nt = 0; nt < 4; ++nt) {
                int f = (nh + nt) * 16 + l15;
                #pragma unroll
                for (int r = 0; r < 4; ++r) {
                    int w = wb + r;
                    if (w < V_) yr[(size_t)w * F_ + f] = acc2[mt][nt][r];
                }
            }
        }
        #pragma unroll
        for (int mt = 0; mt < 2; ++mt)
            #pragma unroll
            for (int nt = 0; nt < 4; ++nt)
                acc2[mt][nt] = zero4;
    };

    // ---- prologue: x(0) staged, x(1) in flight ----
    stage_load(0);
    stage_write();
    stage_load(1);
    __syncthreads();                 // x(0) ready

    // ---- 9 phases: gemm2(q-1) || gemm1(q) ----
    #pragma unroll
    for (int q = 0; q < 9; ++q) {
        const int c = q / 3, k = q % 3;
        if (q > 0) {
            const int pk = (q - 1) % 3;
            gemm2(pk, hT_lds[(q - 1) & 1]);
            if (pk == 2) store_y((q - 1) / 3);
        }
        gemm1(k, hT_lds[q & 1]);
        if (k == 2 && c < CH - 1) {
            stage_write();                     // x(c+1): after last gemm1 read of x(c)
            if (c + 2 < CH) stage_load(c + 2); // issue x(c+2)
        }
        __syncthreads();
    }

    // ---- tail: last gemm2 + store ----
    gemm2(2, hT_lds[0]);
    store_y(CH - 1);
}

extern "C" void kernel_launch(void* const* d_in, const int* in_sizes, int n_in,
                              void* d_out, int out_size, void* d_ws, size_t ws_size,
                              hipStream_t stream) {
    const float* x = (const float*)d_in[0];
    const float* A = (const float*)d_in[1];
    const float* W = (const float*)d_in[2];
    const float* b = (const float*)d_in[3];
    float* yout = (float*)d_out;

    f16* Wt = (f16*)((char*)d_ws + WS_WT);
    f16* A2 = (f16*)((char*)d_ws + WS_A2);

    const int prep_threads = K_ * F_ * C_ + K_ * 32 * 32;  // 27648
    gcn_prep<<<(prep_threads + 255) / 256, 256, 0, stream>>>(A, W, Wt, A2);
    gcn_fused<<<NBLK, 256, 0, stream>>>(x, Wt, A2, b, yout);
}

// Round 7
// 92.276 us; speedup vs baseline: 1.0622x; 1.0622x over previous
//
#include <hip/hip_runtime.h>

// Problem constants
#define N_ 32
#define T_ 300
#define V_ 25
#define C_ 64      // C_IN
#define F_ 128
#define K_ 3
#define TB 2                       // timesteps per chunk
#define CH 3                       // chunks per block
#define TBLK (TB * CH)             // 6 timesteps per block
#define NGRP (T_ / TBLK)           // 50
#define NBLK (N_ * NGRP)           // 1600 blocks

typedef _Float16 f16;
typedef f16  f16x4v __attribute__((ext_vector_type(4)));
typedef f16  f16x8v __attribute__((ext_vector_type(8)));
typedef float f32x4v __attribute__((ext_vector_type(4)));

// workspace byte offsets
#define WS_WT 0         // f16 Wt[384][64]   = 49152 B
#define WS_A2 49152     // f16 A2[3][32][32] =  6144 B

// ---------------- prep: transpose/convert W, pad/convert A ----------------
__global__ void gcn_prep(const float* __restrict__ A, const float* __restrict__ W,
                         f16* __restrict__ Wt, f16* __restrict__ A2) {
    int tid = blockIdx.x * blockDim.x + threadIdx.x;
    if (tid < K_ * F_ * C_) {
        int d = tid >> 6, c = tid & 63;
        Wt[tid] = (f16)W[c * (K_ * F_) + d];
    }
    int t2 = tid - K_ * F_ * C_;
    if (t2 >= 0 && t2 < K_ * 32 * 32) {
        int k = t2 >> 10, r = t2 & 1023, w = r >> 5, v = r & 31;
        float val = (w < V_ && v < V_) ? A[(k * V_ + v) * V_ + w] : 0.0f;
        A2[t2] = (f16)val;
    }
}

// ---------------- fused streaming pipeline ----------------
// per chunk c (2 timesteps), per k: hT[d'][tv] = b[kF+d'] + sum_c x[tv][c]*Wt[kF+d'][c]
//                                   y[t][w][f] += sum_v A2[k][w][v] * hT[f][t*32+v]
// phases q=0..8: gemm2(q-1) || gemm1(q); hT parity q&1; one barrier per phase.
__global__ __launch_bounds__(256)
__attribute__((amdgpu_waves_per_eu(4, 4)))   // pin VGPR budget at 128: stop the
                                             // allocator chasing 8 waves (spilled xstg in r6)
void gcn_fused(
    const float* __restrict__ x, const f16* __restrict__ Wt,
    const f16* __restrict__ A2g, const float* __restrict__ b,
    float* __restrict__ y)
{
    // x chunk: rows tv = t*32+v (v 25..31 zero), 64 cols, XOR-swizzled:
    //   byte = (tv*128 + c*2) ^ ((tv&7)<<4)
    __shared__ __align__(16) f16 x_lds[64 * 64];         // 8192 B
    // hT slices, swizzled: byte = (d*128 + tv*2) ^ ((d&7)<<4)
    __shared__ __align__(16) f16 hT_lds[2][128 * 64];    // 2 x 16384 B
    // total 40960 B -> 4 blocks/CU

    const int tid  = threadIdx.x;
    const int lane = tid & 63;
    const int wave = tid >> 6;
    const int l15  = lane & 15;
    const int lgr  = lane >> 4;       // 0..3
    const int koff = lgr * 8;

    const int n  = blockIdx.x / NGRP;
    const int t0 = (blockIdx.x % NGRP) * TBLK;

    const float* xbase = x + ((size_t)n * T_ + t0) * (V_ * C_);

    // ---- staging (T14): global -> regs (issued early) -> LDS (written late) ----
    float4 xstg[4];
    auto stage_load = [&](int c) {
        const float4* xs = (const float4*)(xbase + (size_t)c * TB * V_ * C_);
        #pragma unroll
        for (int i = 0; i < 4; ++i) {
            int idx = tid + i * 256;
            if (idx < TB * V_ * C_ / 4) xstg[i] = xs[idx];
        }
    };
    auto stage_write = [&]() {
        char* xb = (char*)x_lds;
        #pragma unroll
        for (int i = 0; i < 4; ++i) {
            int idx = tid + i * 256;
            if (idx < TB * V_ * C_ / 4) {
                int e = idx * 4;
                int t = e / (V_ * C_);
                int r = e - t * (V_ * C_);
                int v = r >> 6, c = r & 63;
                int row = t * 32 + v;
                f16x4v hv;
                hv[0] = (f16)xstg[i].x; hv[1] = (f16)xstg[i].y;
                hv[2] = (f16)xstg[i].z; hv[3] = (f16)xstg[i].w;
                int off = (row * 128 + c * 2) ^ ((row & 7) << 4);
                *(f16x4v*)(xb + off) = hv;
            }
        }
    };

    // zero rows v in [25,32) once (staging never touches them)
    if (tid < 224) {
        int e = tid * 4;
        int t = e / (7 * C_);
        int r = e - t * (7 * C_);
        int v = 25 + (r >> 6), c = r & 63;
        int row = t * 32 + v;
        int off = (row * 128 + c * 2) ^ ((row & 7) << 4);
        f16x4v z = {(f16)0.f, (f16)0.f, (f16)0.f, (f16)0.f};
        *(f16x4v*)((char*)x_lds + off) = z;
    }

    // per-lane bias: d = k*128 + wave*32 + nt*16 + l15
    float bias[K_][2];
    #pragma unroll
    for (int k = 0; k < K_; ++k)
        #pragma unroll
        for (int nt = 0; nt < 2; ++nt)
            bias[k][nt] = b[k * F_ + wave * 32 + nt * 16 + l15];

    f32x4v zero4 = {0.f, 0.f, 0.f, 0.f};
    f32x4v acc2[2][4];
    #pragma unroll
    for (int mt = 0; mt < 2; ++mt)
        #pragma unroll
        for (int nt = 0; nt < 4; ++nt)
            acc2[mt][nt] = zero4;

    const int t  = wave >> 1;          // step-2 timestep within chunk
    const int nh = (wave & 1) * 4;     // step-2 f-half
    const f16* wrow = Wt + (size_t)(wave * 32 + l15) * C_ + koff;

    // ---- GEMM1: D[tv][d'] -> hT buf (+bias) ----
    auto gemm1 = [&](int k, f16* buf) {
        f16x8v wfr[2][2];
        #pragma unroll
        for (int nt = 0; nt < 2; ++nt)
            #pragma unroll
            for (int kt = 0; kt < 2; ++kt)
                wfr[nt][kt] = *(const f16x8v*)(wrow + (size_t)(k * F_ + nt * 16) * C_ + kt * 32);
        f16x8v xa[4][2];
        #pragma unroll
        for (int mt = 0; mt < 4; ++mt) {
            int row = mt * 16 + l15;
            #pragma unroll
            for (int kt = 0; kt < 2; ++kt) {
                int off = (row * 128 + (kt * 32 + koff) * 2) ^ ((row & 7) << 4);
                xa[mt][kt] = *(const f16x8v*)((const char*)x_lds + off);
            }
        }
        f32x4v acc1[4][2];
        #pragma unroll
        for (int mt = 0; mt < 4; ++mt)
            #pragma unroll
            for (int nt = 0; nt < 2; ++nt)
                acc1[mt][nt] = zero4;
        #pragma unroll
        for (int kt = 0; kt < 2; ++kt)
            #pragma unroll
            for (int mt = 0; mt < 4; ++mt)
                #pragma unroll
                for (int nt = 0; nt < 2; ++nt)
                    acc1[mt][nt] = __builtin_amdgcn_mfma_f32_16x16x32_f16(
                        xa[mt][kt], wfr[nt][kt], acc1[mt][nt], 0, 0, 0);
        char* hb = (char*)buf;
        #pragma unroll
        for (int mt = 0; mt < 4; ++mt)
            #pragma unroll
            for (int nt = 0; nt < 2; ++nt) {
                int d = wave * 32 + nt * 16 + l15;
                float bv = bias[k][nt];
                f16x4v h4;
                #pragma unroll
                for (int r = 0; r < 4; ++r) h4[r] = (f16)(acc1[mt][nt][r] + bv);
                int off = (d * 128 + (mt * 16 + lgr * 4) * 2) ^ ((d & 7) << 4);
                *(f16x4v*)(hb + off) = h4;
            }
    };

    // ---- GEMM2: acc2 += A2_k @ hT ----
    auto gemm2 = [&](int k, const f16* buf) {
        f16x8v a2f[2];
        #pragma unroll
        for (int mt = 0; mt < 2; ++mt)
            a2f[mt] = *(const f16x8v*)(A2g + ((size_t)(k * 32 + mt * 16 + l15) * 32 + koff));
        const char* hb = (const char*)buf;
        #pragma unroll
        for (int nt = 0; nt < 4; ++nt) {
            int f = (nh + nt) * 16 + l15;
            int off = (f * 128 + (t * 32 + koff) * 2) ^ ((f & 7) << 4);
            f16x8v bv = *(const f16x8v*)(hb + off);
            #pragma unroll
            for (int mt = 0; mt < 2; ++mt)
                acc2[mt][nt] = __builtin_amdgcn_mfma_f32_16x16x32_f16(
                    a2f[mt], bv, acc2[mt][nt], 0, 0, 0);
        }
    };

    // ---- store y for chunk cc, then reset acc2 ----
    auto store_y = [&](int cc) {
        float* yr = y + (((size_t)n * T_ + (t0 + cc * TB + t)) * V_) * F_;
        #pragma unroll
        for (int mt = 0; mt < 2; ++mt) {
            int wb = mt * 16 + lgr * 4;
            #pragma unroll
            for (int nt = 0; nt < 4; ++nt) {
                int f = (nh + nt) * 16 + l15;
                #pragma unroll
                for (int r = 0; r < 4; ++r) {
                    int w = wb + r;
                    if (w < V_) yr[(size_t)w * F_ + f] = acc2[mt][nt][r];
                }
            }
        }
        #pragma unroll
        for (int mt = 0; mt < 2; ++mt)
            #pragma unroll
            for (int nt = 0; nt < 4; ++nt)
                acc2[mt][nt] = zero4;
    };

    // ---- prologue: x(0) staged, x(1) in flight ----
    stage_load(0);
    stage_write();
    stage_load(1);
    __syncthreads();                 // x(0) ready

    // ---- 9 phases: gemm2(q-1) || gemm1(q) ----
    #pragma unroll
    for (int q = 0; q < 9; ++q) {
        const int c = q / 3, k = q % 3;
        if (q > 0) {
            const int pk = (q - 1) % 3;
            gemm2(pk, hT_lds[(q - 1) & 1]);
            if (pk == 2) store_y((q - 1) / 3);
        }
        gemm1(k, hT_lds[q & 1]);
        if (k == 2 && c < CH - 1) {
            __syncthreads();                   // all gemm1 x-reads of chunk c done (race fix)
            stage_write();                     // x(c+1) -> LDS
            if (c + 2 < CH) stage_load(c + 2); // issue x(c+2)
        }
        __syncthreads();
    }

    // ---- tail: last gemm2 + store ----
    gemm2(2, hT_lds[0]);
    store_y(CH - 1);
}

extern "C" void kernel_launch(void* const* d_in, const int* in_sizes, int n_in,
                              void* d_out, int out_size, void* d_ws, size_t ws_size,
                              hipStream_t stream) {
    const float* x = (const float*)d_in[0];
    const float* A = (const float*)d_in[1];
    const float* W = (const float*)d_in[2];
    const float* b = (const float*)d_in[3];
    float* yout = (float*)d_out;

    f16* Wt = (f16*)((char*)d_ws + WS_WT);
    f16* A2 = (f16*)((char*)d_ws + WS_A2);

    const int prep_threads = K_ * F_ * C_ + K_ * 32 * 32;  // 27648
    gcn_prep<<<(prep_threads + 255) / 256, 256, 0, stream>>>(A, W, Wt, A2);
    gcn_fused<<<NBLK, 256, 0, stream>>>(x, Wt, A2, b, yout);
}